// Round 15
// baseline (227.745 us; speedup 1.0000x reference)
//
#include <hip/hip_runtime.h>

#define N_NODES 500000
#define N_EDGES 5000000
#define NB_C 489          // ceil(N_NODES/1024) buckets of 1024 nodes (dst>>10)
#define PB 512            // partition blocks for hist/place
#define EPB 9768          // edges per partition block (mult of 4; PB*EPB >= N_EDGES)
#define SRC_MASK 0xFFFFFu // low 20 bits = src (src < 2^19)

// ===========================================================================
// FAST PATH: radix-bucket edges by dst>>10, then CSR-ify within each bucket.
// agg kernels are atomic-free streaming over node-sorted runs.
// ===========================================================================

// K1: per-block histogram of dst buckets. hist[block][bin], coalesced row write.
__global__ __launch_bounds__(1024)
void hist_kernel(const int* __restrict__ dst, unsigned* __restrict__ hist) {
    __shared__ unsigned h[NB_C];
    for (int i = threadIdx.x; i < NB_C; i += 1024) h[i] = 0u;
    __syncthreads();
    const int b = blockIdx.x;
    const long s0 = (long)b * EPB;
    const int n = (int)min((long)EPB, (long)N_EDGES - s0);
    const int4* d4 = (const int4*)(dst + s0);
    const int n4 = n >> 2;  // n always a multiple of 4
    for (int i = threadIdx.x; i < n4; i += 1024) {
        int4 d = d4[i];
        atomicAdd(&h[d.x >> 10], 1u);
        atomicAdd(&h[d.y >> 10], 1u);
        atomicAdd(&h[d.z >> 10], 1u);
        atomicAdd(&h[d.w >> 10], 1u);
    }
    __syncthreads();
    unsigned* row = hist + (size_t)b * NB_C;
    for (int i = threadIdx.x; i < NB_C; i += 1024) row[i] = h[i];
}

// K2: per-bin exclusive prefix over the PB block counts (in place) + bin total.
__global__ __launch_bounds__(512)
void prefix_kernel(unsigned* __restrict__ hist, unsigned* __restrict__ binTotal) {
    __shared__ unsigned A[PB], B[PB];
    const int bin = blockIdx.x;
    const int t = threadIdx.x;
    const unsigned c = hist[(size_t)t * NB_C + bin];
    A[t] = c;
    __syncthreads();
    unsigned* cur = A; unsigned* nxt = B;
    for (int off = 1; off < PB; off <<= 1) {
        nxt[t] = cur[t] + (t >= off ? cur[t - off] : 0u);
        __syncthreads();
        unsigned* tmp = cur; cur = nxt; nxt = tmp;
    }
    hist[(size_t)t * NB_C + bin] = cur[t] - c;      // exclusive prefix
    if (t == PB - 1) binTotal[bin] = cur[PB - 1];   // total for this bin
}

// K2b: exclusive scan of the NB_C bin totals -> binStart[0..NB_C].
__global__ __launch_bounds__(512)
void binscan_kernel(const unsigned* __restrict__ binTotal,
                    unsigned* __restrict__ binStart) {
    __shared__ unsigned A[512], B[512];
    const int t = threadIdx.x;
    A[t] = (t < NB_C) ? binTotal[t] : 0u;
    __syncthreads();
    unsigned* cur = A; unsigned* nxt = B;
    for (int off = 1; off < 512; off <<= 1) {
        nxt[t] = cur[t] + (t >= off ? cur[t - off] : 0u);
        __syncthreads();
        unsigned* tmp = cur; cur = nxt; nxt = tmp;
    }
    if (t < NB_C) binStart[t] = (t == 0) ? 0u : cur[t - 1];
    if (t == 0) binStart[NB_C] = cur[NB_C - 1];
}

// K3: LDS counting-sort place. Local bin counts come from row-diffs of the
// prefixed hist (no dst re-read, no LDS histogram). Burst-coalesced run writes.
__global__ __launch_bounds__(1024)
void place_kernel(const int* __restrict__ src, const int* __restrict__ dst,
                  const unsigned* __restrict__ hist,      // exclusive-prefixed
                  const unsigned* __restrict__ binTotal,
                  const unsigned* __restrict__ binStart,
                  unsigned* __restrict__ edgebuf) {
    __shared__ unsigned lcnt[512], lstart[512], gbase[512], bump[512];
    __shared__ unsigned scanA[1024], scanB[1024];
    __shared__ unsigned recs[EPB];     // 39 KB sorted records

    const int b = blockIdx.x;
    const int t = threadIdx.x;
    const unsigned* row  = hist + (size_t)b * NB_C;
    const unsigned* row1 = hist + (size_t)(b + 1) * NB_C;
    for (int i = t; i < NB_C; i += 1024) {
        const unsigned p = row[i];
        lcnt[i]  = (b < PB - 1) ? (row1[i] - p) : (binTotal[i] - p);
        gbase[i] = binStart[i] + p;
        bump[i]  = 0u;
    }
    __syncthreads();
    // exclusive scan lcnt -> lstart (1024-wide, padded with zeros)
    scanA[t] = (t < NB_C) ? lcnt[t] : 0u;
    __syncthreads();
    unsigned* cur = scanA; unsigned* nxt = scanB;
    for (int off = 1; off < 1024; off <<= 1) {
        nxt[t] = cur[t] + (t >= off ? cur[t - off] : 0u);
        __syncthreads();
        unsigned* tmp = cur; cur = nxt; nxt = tmp;
    }
    if (t < NB_C) lstart[t] = cur[t] - lcnt[t];
    __syncthreads();
    // fill sorted LDS records
    const long s0 = (long)b * EPB;
    const int n = (int)min((long)EPB, (long)N_EDGES - s0);
    const int4* s4 = (const int4*)(src + s0);
    const int4* d4 = (const int4*)(dst + s0);
    const int n4 = n >> 2;
    for (int i = t; i < n4; i += 1024) {
        int4 s = s4[i];
        int4 d = d4[i];
        unsigned bin, pos;
        bin = (unsigned)d.x >> 10;
        pos = lstart[bin] + atomicAdd(&bump[bin], 1u);
        recs[pos] = ((unsigned)(d.x & 1023) << 20) | (unsigned)s.x;
        bin = (unsigned)d.y >> 10;
        pos = lstart[bin] + atomicAdd(&bump[bin], 1u);
        recs[pos] = ((unsigned)(d.y & 1023) << 20) | (unsigned)s.y;
        bin = (unsigned)d.z >> 10;
        pos = lstart[bin] + atomicAdd(&bump[bin], 1u);
        recs[pos] = ((unsigned)(d.z & 1023) << 20) | (unsigned)s.z;
        bin = (unsigned)d.w >> 10;
        pos = lstart[bin] + atomicAdd(&bump[bin], 1u);
        recs[pos] = ((unsigned)(d.w & 1023) << 20) | (unsigned)s.w;
    }
    __syncthreads();
    // burst-copy each bin run (wave per bin, contiguous lanes)
    const int wave = t >> 6;
    const int lane = t & 63;
    for (int bin = wave; bin < NB_C; bin += 16) {
        const unsigned L  = lcnt[bin];
        const unsigned gs = gbase[bin];
        const unsigned ls = lstart[bin];
        for (unsigned i = lane; i < L; i += 64)
            edgebuf[gs + i] = recs[ls + i];
    }
}

// K4: per-bucket CSR-ify. Count per-node degree, scan -> row pointers nstart,
// write dinv/u, then scatter records node-grouped into edgebuf2 (the bin's
// 40 KB window is block-exclusive -> full-line L2 writebacks).
__global__ __launch_bounds__(1024)
void deg_sort_kernel(const unsigned* __restrict__ edgebuf,
                     const unsigned* __restrict__ binStart,
                     const float* __restrict__ x,
                     float* __restrict__ dinv, float* __restrict__ u,
                     unsigned* __restrict__ nstart,
                     unsigned* __restrict__ edgebuf2) {
    __shared__ unsigned cnt[1024], ns[1024], bump[1024];
    __shared__ unsigned scanA[1024], scanB[1024];
    const int t = threadIdx.x;
    cnt[t] = 0u;
    bump[t] = 0u;
    __syncthreads();
    const int bin = blockIdx.x;
    const unsigned e0 = binStart[bin], e1 = binStart[bin + 1];
    const unsigned ea = (e0 + 3u) & ~3u;
    const unsigned eb = e1 & ~3u;
    for (unsigned e = e0 + t; e < min(ea, e1); e += 1024)
        atomicAdd(&cnt[edgebuf[e] >> 20], 1u);
    if (ea < eb) {
        const uint4* p4 = (const uint4*)(edgebuf + ea);
        const unsigned nv = (eb - ea) >> 2;
        for (unsigned i = t; i < nv; i += 1024) {
            uint4 r = p4[i];
            atomicAdd(&cnt[r.x >> 20], 1u);
            atomicAdd(&cnt[r.y >> 20], 1u);
            atomicAdd(&cnt[r.z >> 20], 1u);
            atomicAdd(&cnt[r.w >> 20], 1u);
        }
    }
    for (unsigned e = max(eb, min(ea, e1)) + t; e < e1; e += 1024)
        atomicAdd(&cnt[edgebuf[e] >> 20], 1u);
    __syncthreads();
    // exclusive scan cnt -> ns
    scanA[t] = cnt[t];
    __syncthreads();
    unsigned* cur = scanA; unsigned* nxt = scanB;
    for (int off = 1; off < 1024; off <<= 1) {
        nxt[t] = cur[t] + (t >= off ? cur[t - off] : 0u);
        __syncthreads();
        unsigned* tmp = cur; cur = nxt; nxt = tmp;
    }
    ns[t] = cur[t] - cnt[t];
    // row pointers for ALL 1024 slots (padding slots -> e1, empty runs)
    const int node = (bin << 10) + t;
    nstart[node] = e0 + ns[t];
    if (node < N_NODES) {
        float di = rsqrtf((float)cnt[t] + 1.0f);
        dinv[node] = di;
        u[node] = x[node] * di;
    }
    __syncthreads();
    // scatter node-grouped (re-stream is L2/L3-hot)
    for (unsigned e = e0 + t; e < e1; e += 1024) {
        const unsigned rec = edgebuf[e];
        const unsigned l = rec >> 20;
        const unsigned pos = ns[l] + atomicAdd(&bump[l], 1u);
        edgebuf2[e0 + pos] = rec;
    }
}

// K5: agg1 — atomic-free: thread=node, serial-sum its contiguous run + MLP.
__global__ __launch_bounds__(1024)
void agg1_kernel(const unsigned* __restrict__ edgebuf2,
                 const unsigned* __restrict__ nstart,
                 const float* __restrict__ dinv, const float* __restrict__ u,
                 const float* __restrict__ W1, const float* __restrict__ b1,
                 const float* __restrict__ W2, float* __restrict__ w) {
    const int node = blockIdx.x * 1024 + threadIdx.x;
    if (node >= N_NODES) return;
    const unsigned rs = nstart[node], re = nstart[node + 1];
    float acc = 0.0f;
    for (unsigned e = rs; e < re; ++e)
        acc += u[edgebuf2[e] & SRC_MASK];
    const float di = dinv[node];
    const float s = di * (acc + u[node]);
    float tt = 0.0f;
#pragma unroll
    for (int j = 0; j < 16; ++j) {
        float h = fmaf(W1[j], s, b1[j]);
        h = fmaxf(h, 0.0f);
        tt = fmaf(h, W2[j], tt);
    }
    w[node] = tt * di;
}

// K6: agg2 — atomic-free second aggregation + epilogue.
__global__ __launch_bounds__(1024)
void agg2_kernel(const unsigned* __restrict__ edgebuf2,
                 const unsigned* __restrict__ nstart,
                 const float* __restrict__ dinv, const float* __restrict__ w,
                 const float* __restrict__ b2, float* __restrict__ out) {
    const int node = blockIdx.x * 1024 + threadIdx.x;
    if (node >= N_NODES) return;
    const unsigned rs = nstart[node], re = nstart[node + 1];
    float acc = 0.0f;
    for (unsigned e = rs; e < re; ++e)
        acc += w[edgebuf2[e] & SRC_MASK];
    out[node] = fmaf(dinv[node], acc + w[node], b2[0]);
}

// ===========================================================================
// FALLBACK PATH (verified round-4 kernels) — used only if ws_size is too small.
// ===========================================================================
__global__ __launch_bounds__(256)
void deg_kernel(const int* __restrict__ dst, float* __restrict__ deg) {
    const int tid = blockIdx.x * blockDim.x + threadIdx.x;
    const int stride = gridDim.x * blockDim.x;
    const int nvec = N_EDGES / 4;
    const int4* dst4 = (const int4*)dst;
    for (int i = tid; i < nvec; i += stride) {
        int4 d = dst4[i];
        atomicAdd(&deg[d.x], 1.0f);
        atomicAdd(&deg[d.y], 1.0f);
        atomicAdd(&deg[d.z], 1.0f);
        atomicAdd(&deg[d.w], 1.0f);
    }
}
__global__ __launch_bounds__(256)
void node1_kernel(const float* __restrict__ x, float* __restrict__ deg_to_dinv,
                  float* __restrict__ u) {
    const int i = blockIdx.x * blockDim.x + threadIdx.x;
    if (i >= N_NODES) return;
    float di = rsqrtf(deg_to_dinv[i] + 1.0f);
    deg_to_dinv[i] = di;
    u[i] = x[i] * di;
}
__global__ __launch_bounds__(256)
void scatter_kernel(const int* __restrict__ src, const int* __restrict__ dst,
                    const float* __restrict__ val, float* __restrict__ acc) {
    const int tid = blockIdx.x * blockDim.x + threadIdx.x;
    const int stride = gridDim.x * blockDim.x;
    const int nvec = N_EDGES / 4;
    const int4* src4 = (const int4*)src;
    const int4* dst4 = (const int4*)dst;
    for (int i = tid; i < nvec; i += stride) {
        int4 s = src4[i];
        int4 d = dst4[i];
        atomicAdd(&acc[d.x], val[s.x]);
        atomicAdd(&acc[d.y], val[s.y]);
        atomicAdd(&acc[d.z], val[s.z]);
        atomicAdd(&acc[d.w], val[s.w]);
    }
}
__global__ __launch_bounds__(256)
void node2_kernel(const float* __restrict__ dinv, const float* __restrict__ u,
                  const float* __restrict__ acc1, const float* __restrict__ W1,
                  const float* __restrict__ b1, const float* __restrict__ W2,
                  float* __restrict__ w) {
    const int i = blockIdx.x * blockDim.x + threadIdx.x;
    if (i >= N_NODES) return;
    float di = dinv[i];
    float s = di * (acc1[i] + u[i]);
    float t = 0.0f;
#pragma unroll
    for (int j = 0; j < 16; ++j) {
        float h = fmaf(W1[j], s, b1[j]);
        h = fmaxf(h, 0.0f);
        t = fmaf(h, W2[j], t);
    }
    w[i] = t * di;
}
__global__ __launch_bounds__(256)
void final_kernel(const float* __restrict__ dinv, const float* __restrict__ w,
                  const float* __restrict__ acc2, const float* __restrict__ b2,
                  float* __restrict__ out) {
    const int i = blockIdx.x * blockDim.x + threadIdx.x;
    if (i >= N_NODES) return;
    float wi = w[i];
    out[i] = fmaf(dinv[i], acc2[i] + wi, b2[0]);
}

// ===========================================================================
extern "C" void kernel_launch(void* const* d_in, const int* in_sizes, int n_in,
                              void* d_out, int out_size, void* d_ws, size_t ws_size,
                              hipStream_t stream) {
    const float* x  = (const float*)d_in[0];
    const float* W1 = (const float*)d_in[1];
    const float* b1 = (const float*)d_in[2];
    const float* W2 = (const float*)d_in[3];
    const float* b2 = (const float*)d_in[4];
    const int* edge_index = (const int*)d_in[5];
    const int* src = edge_index;
    const int* dst = edge_index + N_EDGES;
    float* out = (float*)d_out;
    char* ws = (char*)d_ws;

    // Fast-path workspace layout (byte offsets, 16B-aligned):
    const size_t OFF_EDGEBUF  = 0;          // u32[N_EDGES]       20,000,000
    const size_t OFF_HIST     = 20000000;   // u32[PB*NB_C]        1,001,472
    const size_t OFF_BINSTART = 21001472;   // u32[NB_C+1]             1,960
    const size_t OFF_BINTOTAL = 21003440;   // u32[NB_C]               1,956
    const size_t OFF_NSTART   = 21005408;   // u32[NB_C*1024]      2,002,944
    const size_t OFF_DINV     = 23008352;   // f32[N]              2,000,000
    const size_t OFF_U        = 25008352;   // f32[N]
    const size_t OFF_W        = 27008352;   // f32[N]
    const size_t OFF_EDGEBUF2 = 29008352;   // u32[N_EDGES]       20,000,000
    const size_t FAST_WS      = 49008352;   // ~49 MB (ws is ~268 MB per profile)

    if (ws_size >= FAST_WS) {
        unsigned* edgebuf  = (unsigned*)(ws + OFF_EDGEBUF);
        unsigned* hist     = (unsigned*)(ws + OFF_HIST);
        unsigned* binStart = (unsigned*)(ws + OFF_BINSTART);
        unsigned* binTotal = (unsigned*)(ws + OFF_BINTOTAL);
        unsigned* nstart   = (unsigned*)(ws + OFF_NSTART);
        float* dinv = (float*)(ws + OFF_DINV);
        float* u    = (float*)(ws + OFF_U);
        float* w    = (float*)(ws + OFF_W);
        unsigned* edgebuf2 = (unsigned*)(ws + OFF_EDGEBUF2);

        hist_kernel<<<PB, 1024, 0, stream>>>(dst, hist);
        prefix_kernel<<<NB_C, PB, 0, stream>>>(hist, binTotal);
        binscan_kernel<<<1, 512, 0, stream>>>(binTotal, binStart);
        place_kernel<<<PB, 1024, 0, stream>>>(src, dst, hist, binTotal, binStart, edgebuf);
        deg_sort_kernel<<<NB_C, 1024, 0, stream>>>(edgebuf, binStart, x, dinv, u,
                                                   nstart, edgebuf2);
        agg1_kernel<<<NB_C, 1024, 0, stream>>>(edgebuf2, nstart, dinv, u,
                                               W1, b1, W2, w);
        agg2_kernel<<<NB_C, 1024, 0, stream>>>(edgebuf2, nstart, dinv, w, b2, out);
    } else {
        // Fallback: verified global-atomic path.
        float* buf  = (float*)d_ws;
        float* dinv = buf;
        float* acc1 = buf + 1 * N_NODES;
        float* acc2 = buf + 2 * N_NODES;
        float* u    = buf + 3 * N_NODES;
        float* w    = out;
        hipMemsetAsync(d_ws, 0, 3 * N_NODES * sizeof(float), stream);
        const int nodeBlocks = (N_NODES + 255) / 256;
        const int edgeBlocks = 2048;
        deg_kernel<<<edgeBlocks, 256, 0, stream>>>(dst, dinv);
        node1_kernel<<<nodeBlocks, 256, 0, stream>>>(x, dinv, u);
        scatter_kernel<<<edgeBlocks, 256, 0, stream>>>(src, dst, u, acc1);
        node2_kernel<<<nodeBlocks, 256, 0, stream>>>(dinv, u, acc1, W1, b1, W2, w);
        scatter_kernel<<<edgeBlocks, 256, 0, stream>>>(src, dst, w, acc2);
        final_kernel<<<nodeBlocks, 256, 0, stream>>>(dinv, w, acc2, b2, out);
    }
}

// Round 17
// 177.858 us; speedup vs baseline: 1.2805x; 1.2805x over previous
//
#include <hip/hip_runtime.h>

#define N_NODES 500000
#define N_EDGES 5000000
#define NB_C 489          // ceil(N_NODES/1024) buckets of 1024 nodes (dst>>10)
#define PB 512            // partition blocks for hist/place
#define EPB 9768          // edges per partition block (mult of 4; PB*EPB >= N_EDGES)
#define SRC_MASK 0xFFFFFu // low 20 bits = src (src < 2^19)

// ===========================================================================
// FAST PATH: zero global atomics. Bucket-sort edges by dst>>10, aggregate in LDS.
// place = LDS counting sort (counts from hist row-diffs) + burst-coalesced writes.
// ===========================================================================

// K1: per-block histogram of dst buckets. hist[block][bin], coalesced row write.
__global__ __launch_bounds__(1024)
void hist_kernel(const int* __restrict__ dst, unsigned* __restrict__ hist) {
    __shared__ unsigned h[NB_C];
    for (int i = threadIdx.x; i < NB_C; i += 1024) h[i] = 0u;
    __syncthreads();
    const int b = blockIdx.x;
    const long s0 = (long)b * EPB;
    const int n = (int)min((long)EPB, (long)N_EDGES - s0);
    const int4* d4 = (const int4*)(dst + s0);
    const int n4 = n >> 2;  // n always a multiple of 4
    for (int i = threadIdx.x; i < n4; i += 1024) {
        int4 d = d4[i];
        atomicAdd(&h[d.x >> 10], 1u);
        atomicAdd(&h[d.y >> 10], 1u);
        atomicAdd(&h[d.z >> 10], 1u);
        atomicAdd(&h[d.w >> 10], 1u);
    }
    __syncthreads();
    unsigned* row = hist + (size_t)b * NB_C;
    for (int i = threadIdx.x; i < NB_C; i += 1024) row[i] = h[i];
}

// K2: per-bin exclusive prefix over the PB block counts (in place) + bin total.
__global__ __launch_bounds__(512)
void prefix_kernel(unsigned* __restrict__ hist, unsigned* __restrict__ binTotal) {
    __shared__ unsigned A[PB], B[PB];
    const int bin = blockIdx.x;
    const int t = threadIdx.x;
    const unsigned c = hist[(size_t)t * NB_C + bin];
    A[t] = c;
    __syncthreads();
    unsigned* cur = A; unsigned* nxt = B;
    for (int off = 1; off < PB; off <<= 1) {
        nxt[t] = cur[t] + (t >= off ? cur[t - off] : 0u);
        __syncthreads();
        unsigned* tmp = cur; cur = nxt; nxt = tmp;
    }
    hist[(size_t)t * NB_C + bin] = cur[t] - c;      // exclusive prefix
    if (t == PB - 1) binTotal[bin] = cur[PB - 1];   // total for this bin
}

// K2b: exclusive scan of the NB_C bin totals -> binStart[0..NB_C].
__global__ __launch_bounds__(512)
void binscan_kernel(const unsigned* __restrict__ binTotal,
                    unsigned* __restrict__ binStart) {
    __shared__ unsigned A[512], B[512];
    const int t = threadIdx.x;
    A[t] = (t < NB_C) ? binTotal[t] : 0u;
    __syncthreads();
    unsigned* cur = A; unsigned* nxt = B;
    for (int off = 1; off < 512; off <<= 1) {
        nxt[t] = cur[t] + (t >= off ? cur[t - off] : 0u);
        __syncthreads();
        unsigned* tmp = cur; cur = nxt; nxt = tmp;
    }
    if (t < NB_C) binStart[t] = (t == 0) ? 0u : cur[t - 1];
    if (t == 0) binStart[NB_C] = cur[NB_C - 1];
}

// K3: LDS counting-sort place. Local bin counts come from row-diffs of the
// prefixed hist (no dst re-read, no LDS histogram). Burst-coalesced run writes.
__global__ __launch_bounds__(1024)
void place_kernel(const int* __restrict__ src, const int* __restrict__ dst,
                  const unsigned* __restrict__ hist,      // exclusive-prefixed
                  const unsigned* __restrict__ binTotal,
                  const unsigned* __restrict__ binStart,
                  unsigned* __restrict__ edgebuf) {
    __shared__ unsigned lcnt[512], lstart[512], gbase[512], bump[512];
    __shared__ unsigned scanA[1024], scanB[1024];
    __shared__ unsigned recs[EPB];     // 39 KB sorted records

    const int b = blockIdx.x;
    const int t = threadIdx.x;
    const unsigned* row  = hist + (size_t)b * NB_C;
    const unsigned* row1 = hist + (size_t)(b + 1) * NB_C;
    for (int i = t; i < NB_C; i += 1024) {
        const unsigned p = row[i];
        lcnt[i]  = (b < PB - 1) ? (row1[i] - p) : (binTotal[i] - p);
        gbase[i] = binStart[i] + p;
        bump[i]  = 0u;
    }
    __syncthreads();
    // exclusive scan lcnt -> lstart (1024-wide, padded with zeros)
    scanA[t] = (t < NB_C) ? lcnt[t] : 0u;
    __syncthreads();
    unsigned* cur = scanA; unsigned* nxt = scanB;
    for (int off = 1; off < 1024; off <<= 1) {
        nxt[t] = cur[t] + (t >= off ? cur[t - off] : 0u);
        __syncthreads();
        unsigned* tmp = cur; cur = nxt; nxt = tmp;
    }
    if (t < NB_C) lstart[t] = cur[t] - lcnt[t];
    __syncthreads();
    // fill sorted LDS records
    const long s0 = (long)b * EPB;
    const int n = (int)min((long)EPB, (long)N_EDGES - s0);
    const int4* s4 = (const int4*)(src + s0);
    const int4* d4 = (const int4*)(dst + s0);
    const int n4 = n >> 2;
    for (int i = t; i < n4; i += 1024) {
        int4 s = s4[i];
        int4 d = d4[i];
        unsigned bin, pos;
        bin = (unsigned)d.x >> 10;
        pos = lstart[bin] + atomicAdd(&bump[bin], 1u);
        recs[pos] = ((unsigned)(d.x & 1023) << 20) | (unsigned)s.x;
        bin = (unsigned)d.y >> 10;
        pos = lstart[bin] + atomicAdd(&bump[bin], 1u);
        recs[pos] = ((unsigned)(d.y & 1023) << 20) | (unsigned)s.y;
        bin = (unsigned)d.z >> 10;
        pos = lstart[bin] + atomicAdd(&bump[bin], 1u);
        recs[pos] = ((unsigned)(d.z & 1023) << 20) | (unsigned)s.z;
        bin = (unsigned)d.w >> 10;
        pos = lstart[bin] + atomicAdd(&bump[bin], 1u);
        recs[pos] = ((unsigned)(d.w & 1023) << 20) | (unsigned)s.w;
    }
    __syncthreads();
    // burst-copy each bin run (wave per bin, contiguous lanes)
    const int wave = t >> 6;
    const int lane = t & 63;
    for (int bin = wave; bin < NB_C; bin += 16) {
        const unsigned L  = lcnt[bin];
        const unsigned gs = gbase[bin];
        const unsigned ls = lstart[bin];
        for (unsigned i = lane; i < L; i += 64)
            edgebuf[gs + i] = recs[ls + i];
    }
}

// K4a: per-bucket in-degree -> dinv = rsqrt(deg+1); u = x*dinv. (node1 fused)
__global__ __launch_bounds__(1024)
void deg_dinv_kernel(const unsigned* __restrict__ edgebuf,
                     const unsigned* __restrict__ binStart,
                     const float* __restrict__ x,
                     float* __restrict__ dinv, float* __restrict__ u) {
    __shared__ unsigned cnt[1024];
    cnt[threadIdx.x] = 0u;
    __syncthreads();
    const int bin = blockIdx.x;
    const unsigned e0 = binStart[bin], e1 = binStart[bin + 1];
    const unsigned ea = (e0 + 3u) & ~3u;
    const unsigned eb = e1 & ~3u;
    for (unsigned e = e0 + threadIdx.x; e < min(ea, e1); e += 1024)
        atomicAdd(&cnt[edgebuf[e] >> 20], 1u);
    if (ea < eb) {
        const uint4* p4 = (const uint4*)(edgebuf + ea);
        const unsigned nv = (eb - ea) >> 2;
        for (unsigned i = threadIdx.x; i < nv; i += 1024) {
            uint4 r = p4[i];
            atomicAdd(&cnt[r.x >> 20], 1u);
            atomicAdd(&cnt[r.y >> 20], 1u);
            atomicAdd(&cnt[r.z >> 20], 1u);
            atomicAdd(&cnt[r.w >> 20], 1u);
        }
    }
    for (unsigned e = max(eb, min(ea, e1)) + threadIdx.x; e < e1; e += 1024)
        atomicAdd(&cnt[edgebuf[e] >> 20], 1u);
    __syncthreads();
    const int node = (bin << 10) + threadIdx.x;
    if (node < N_NODES) {
        float di = rsqrtf((float)cnt[threadIdx.x] + 1.0f);
        dinv[node] = di;
        u[node] = x[node] * di;
    }
}

// K4b: agg1 (sum u[src] per node, LDS) + collapsed 16-wide MLP -> w. (node2 fused)
__global__ __launch_bounds__(1024)
void agg1_kernel(const unsigned* __restrict__ edgebuf,
                 const unsigned* __restrict__ binStart,
                 const float* __restrict__ dinv, const float* __restrict__ u,
                 const float* __restrict__ W1, const float* __restrict__ b1,
                 const float* __restrict__ W2, float* __restrict__ w) {
    __shared__ float sum[1024];
    sum[threadIdx.x] = 0.0f;
    __syncthreads();
    const int bin = blockIdx.x;
    const unsigned e0 = binStart[bin], e1 = binStart[bin + 1];
    const unsigned ea = (e0 + 3u) & ~3u;
    const unsigned eb = e1 & ~3u;
    for (unsigned e = e0 + threadIdx.x; e < min(ea, e1); e += 1024) {
        unsigned rec = edgebuf[e];
        atomicAdd(&sum[rec >> 20], u[rec & SRC_MASK]);
    }
    if (ea < eb) {
        const uint4* p4 = (const uint4*)(edgebuf + ea);
        const unsigned nv = (eb - ea) >> 2;
        for (unsigned i = threadIdx.x; i < nv; i += 1024) {
            uint4 r = p4[i];
            atomicAdd(&sum[r.x >> 20], u[r.x & SRC_MASK]);
            atomicAdd(&sum[r.y >> 20], u[r.y & SRC_MASK]);
            atomicAdd(&sum[r.z >> 20], u[r.z & SRC_MASK]);
            atomicAdd(&sum[r.w >> 20], u[r.w & SRC_MASK]);
        }
    }
    for (unsigned e = max(eb, min(ea, e1)) + threadIdx.x; e < e1; e += 1024) {
        unsigned rec = edgebuf[e];
        atomicAdd(&sum[rec >> 20], u[rec & SRC_MASK]);
    }
    __syncthreads();
    const int node = (bin << 10) + threadIdx.x;
    if (node < N_NODES) {
        float di = dinv[node];
        float s = di * (sum[threadIdx.x] + u[node]);
        float t = 0.0f;
#pragma unroll
        for (int j = 0; j < 16; ++j) {
            float h = fmaf(W1[j], s, b1[j]);
            h = fmaxf(h, 0.0f);
            t = fmaf(h, W2[j], t);
        }
        w[node] = t * di;
    }
}

// K4c: agg2 (sum w[src] per node, LDS) + final epilogue -> out.
__global__ __launch_bounds__(1024)
void agg2_kernel(const unsigned* __restrict__ edgebuf,
                 const unsigned* __restrict__ binStart,
                 const float* __restrict__ dinv, const float* __restrict__ w,
                 const float* __restrict__ b2, float* __restrict__ out) {
    __shared__ float sum[1024];
    sum[threadIdx.x] = 0.0f;
    __syncthreads();
    const int bin = blockIdx.x;
    const unsigned e0 = binStart[bin], e1 = binStart[bin + 1];
    const unsigned ea = (e0 + 3u) & ~3u;
    const unsigned eb = e1 & ~3u;
    for (unsigned e = e0 + threadIdx.x; e < min(ea, e1); e += 1024) {
        unsigned rec = edgebuf[e];
        atomicAdd(&sum[rec >> 20], w[rec & SRC_MASK]);
    }
    if (ea < eb) {
        const uint4* p4 = (const uint4*)(edgebuf + ea);
        const unsigned nv = (eb - ea) >> 2;
        for (unsigned i = threadIdx.x; i < nv; i += 1024) {
            uint4 r = p4[i];
            atomicAdd(&sum[r.x >> 20], w[r.x & SRC_MASK]);
            atomicAdd(&sum[r.y >> 20], w[r.y & SRC_MASK]);
            atomicAdd(&sum[r.z >> 20], w[r.z & SRC_MASK]);
            atomicAdd(&sum[r.w >> 20], w[r.w & SRC_MASK]);
        }
    }
    for (unsigned e = max(eb, min(ea, e1)) + threadIdx.x; e < e1; e += 1024) {
        unsigned rec = edgebuf[e];
        atomicAdd(&sum[rec >> 20], w[rec & SRC_MASK]);
    }
    __syncthreads();
    const int node = (bin << 10) + threadIdx.x;
    if (node < N_NODES)
        out[node] = fmaf(dinv[node], sum[threadIdx.x] + w[node], b2[0]);
}

// ===========================================================================
// FALLBACK PATH (verified round-4 kernels) — used only if ws_size is too small.
// ===========================================================================
__global__ __launch_bounds__(256)
void deg_kernel(const int* __restrict__ dst, float* __restrict__ deg) {
    const int tid = blockIdx.x * blockDim.x + threadIdx.x;
    const int stride = gridDim.x * blockDim.x;
    const int nvec = N_EDGES / 4;
    const int4* dst4 = (const int4*)dst;
    for (int i = tid; i < nvec; i += stride) {
        int4 d = dst4[i];
        atomicAdd(&deg[d.x], 1.0f);
        atomicAdd(&deg[d.y], 1.0f);
        atomicAdd(&deg[d.z], 1.0f);
        atomicAdd(&deg[d.w], 1.0f);
    }
}
__global__ __launch_bounds__(256)
void node1_kernel(const float* __restrict__ x, float* __restrict__ deg_to_dinv,
                  float* __restrict__ u) {
    const int i = blockIdx.x * blockDim.x + threadIdx.x;
    if (i >= N_NODES) return;
    float di = rsqrtf(deg_to_dinv[i] + 1.0f);
    deg_to_dinv[i] = di;
    u[i] = x[i] * di;
}
__global__ __launch_bounds__(256)
void scatter_kernel(const int* __restrict__ src, const int* __restrict__ dst,
                    const float* __restrict__ val, float* __restrict__ acc) {
    const int tid = blockIdx.x * blockDim.x + threadIdx.x;
    const int stride = gridDim.x * blockDim.x;
    const int nvec = N_EDGES / 4;
    const int4* src4 = (const int4*)src;
    const int4* dst4 = (const int4*)dst;
    for (int i = tid; i < nvec; i += stride) {
        int4 s = src4[i];
        int4 d = dst4[i];
        atomicAdd(&acc[d.x], val[s.x]);
        atomicAdd(&acc[d.y], val[s.y]);
        atomicAdd(&acc[d.z], val[s.z]);
        atomicAdd(&acc[d.w], val[s.w]);
    }
}
__global__ __launch_bounds__(256)
void node2_kernel(const float* __restrict__ dinv, const float* __restrict__ u,
                  const float* __restrict__ acc1, const float* __restrict__ W1,
                  const float* __restrict__ b1, const float* __restrict__ W2,
                  float* __restrict__ w) {
    const int i = blockIdx.x * blockDim.x + threadIdx.x;
    if (i >= N_NODES) return;
    float di = dinv[i];
    float s = di * (acc1[i] + u[i]);
    float t = 0.0f;
#pragma unroll
    for (int j = 0; j < 16; ++j) {
        float h = fmaf(W1[j], s, b1[j]);
        h = fmaxf(h, 0.0f);
        t = fmaf(h, W2[j], t);
    }
    w[i] = t * di;
}
__global__ __launch_bounds__(256)
void final_kernel(const float* __restrict__ dinv, const float* __restrict__ w,
                  const float* __restrict__ acc2, const float* __restrict__ b2,
                  float* __restrict__ out) {
    const int i = blockIdx.x * blockDim.x + threadIdx.x;
    if (i >= N_NODES) return;
    float wi = w[i];
    out[i] = fmaf(dinv[i], acc2[i] + wi, b2[0]);
}

// ===========================================================================
extern "C" void kernel_launch(void* const* d_in, const int* in_sizes, int n_in,
                              void* d_out, int out_size, void* d_ws, size_t ws_size,
                              hipStream_t stream) {
    const float* x  = (const float*)d_in[0];
    const float* W1 = (const float*)d_in[1];
    const float* b1 = (const float*)d_in[2];
    const float* W2 = (const float*)d_in[3];
    const float* b2 = (const float*)d_in[4];
    const int* edge_index = (const int*)d_in[5];
    const int* src = edge_index;
    const int* dst = edge_index + N_EDGES;
    float* out = (float*)d_out;
    char* ws = (char*)d_ws;

    // Fast-path workspace layout (byte offsets, 16B-aligned):
    const size_t OFF_EDGEBUF  = 0;                    // u32[N_EDGES]  20,000,000
    const size_t OFF_HIST     = 20000000;             // u32[PB*NB_C]   1,001,472
    const size_t OFF_BINSTART = 21001472;             // u32[NB_C+1]        1,960
    const size_t OFF_BINTOTAL = 21003440;             // u32[NB_C]          1,956
    const size_t OFF_DINV     = 21005408;             // f32[N]
    const size_t OFF_U        = OFF_DINV + 2000000;
    const size_t OFF_W        = OFF_U + 2000000;
    const size_t FAST_WS      = OFF_W + 2000000;      // ~27.0 MB

    if (ws_size >= FAST_WS) {
        unsigned* edgebuf  = (unsigned*)(ws + OFF_EDGEBUF);
        unsigned* hist     = (unsigned*)(ws + OFF_HIST);
        unsigned* binStart = (unsigned*)(ws + OFF_BINSTART);
        unsigned* binTotal = (unsigned*)(ws + OFF_BINTOTAL);
        float* dinv = (float*)(ws + OFF_DINV);
        float* u    = (float*)(ws + OFF_U);
        float* w    = (float*)(ws + OFF_W);

        hist_kernel<<<PB, 1024, 0, stream>>>(dst, hist);
        prefix_kernel<<<NB_C, PB, 0, stream>>>(hist, binTotal);
        binscan_kernel<<<1, 512, 0, stream>>>(binTotal, binStart);
        place_kernel<<<PB, 1024, 0, stream>>>(src, dst, hist, binTotal, binStart, edgebuf);
        deg_dinv_kernel<<<NB_C, 1024, 0, stream>>>(edgebuf, binStart, x, dinv, u);
        agg1_kernel<<<NB_C, 1024, 0, stream>>>(edgebuf, binStart, dinv, u, W1, b1, W2, w);
        agg2_kernel<<<NB_C, 1024, 0, stream>>>(edgebuf, binStart, dinv, w, b2, out);
    } else {
        // Fallback: verified global-atomic path.
        float* buf  = (float*)d_ws;
        float* dinv = buf;
        float* acc1 = buf + 1 * N_NODES;
        float* acc2 = buf + 2 * N_NODES;
        float* u    = buf + 3 * N_NODES;
        float* w    = out;
        hipMemsetAsync(d_ws, 0, 3 * N_NODES * sizeof(float), stream);
        const int nodeBlocks = (N_NODES + 255) / 256;
        const int edgeBlocks = 2048;
        deg_kernel<<<edgeBlocks, 256, 0, stream>>>(dst, dinv);
        node1_kernel<<<nodeBlocks, 256, 0, stream>>>(x, dinv, u);
        scatter_kernel<<<edgeBlocks, 256, 0, stream>>>(src, dst, u, acc1);
        node2_kernel<<<nodeBlocks, 256, 0, stream>>>(dinv, u, acc1, W1, b1, W2, w);
        scatter_kernel<<<edgeBlocks, 256, 0, stream>>>(src, dst, w, acc2);
        final_kernel<<<nodeBlocks, 256, 0, stream>>>(dinv, w, acc2, b2, out);
    }
}